// Round 2
// baseline (1211.757 us; speedup 1.0000x reference)
//
#include <hip/hip_runtime.h>
#include <stdint.h>

#define NN 50000
#define NE 500000
#define TILE 32
#define BLK 256

__device__ __forceinline__ float silu(float x) { return x / (1.0f + __expf(-x)); }

// ---------- shared register-tiled GEMM core ----------
// C[TILE=32 rows, 128 cols] += A(sA[.][acol + k]) * W[k][j], K in {128, 256}.
// Thread (trow=tid>>5, tcol=tid&31) owns rows trow*4..+3, cols tcol*4..+3.
// W (fp32 row-major [K,128]) streamed through sW in 32-row chunks.
template <int K>
__device__ __forceinline__ void gemm_tile(
    float (&sA)[TILE][264], float (&sW)[32][128],
    const float* __restrict__ W, int acol,
    int tid, int trow, int tcol, float (&acc)[4][4])
{
    const float4* W4 = reinterpret_cast<const float4*>(W);
    for (int k0 = 0; k0 < K; k0 += 32) {
        __syncthreads();
#pragma unroll
        for (int t = 0; t < 4; ++t) {              // 32x128 fp32 chunk = 1024 float4
            int idx = tid + t * BLK;
            int kk = idx >> 5, c4 = idx & 31;      // 32 float4 per row
            *reinterpret_cast<float4*>(&sW[kk][c4 * 4]) = W4[(size_t)(k0 + kk) * 32 + c4];
        }
        __syncthreads();
#pragma unroll
        for (int kq = 0; kq < 8; ++kq) {
            const float4 b0 = *reinterpret_cast<const float4*>(&sW[4 * kq + 0][tcol * 4]);
            const float4 b1 = *reinterpret_cast<const float4*>(&sW[4 * kq + 1][tcol * 4]);
            const float4 b2 = *reinterpret_cast<const float4*>(&sW[4 * kq + 2][tcol * 4]);
            const float4 b3 = *reinterpret_cast<const float4*>(&sW[4 * kq + 3][tcol * 4]);
#pragma unroll
            for (int i = 0; i < 4; ++i) {
                const float4 a = *reinterpret_cast<const float4*>(&sA[trow * 4 + i][acol + k0 + 4 * kq]);
                acc[i][0] = fmaf(a.x, b0.x, fmaf(a.y, b1.x, fmaf(a.z, b2.x, fmaf(a.w, b3.x, acc[i][0]))));
                acc[i][1] = fmaf(a.x, b0.y, fmaf(a.y, b1.y, fmaf(a.z, b2.y, fmaf(a.w, b3.y, acc[i][1]))));
                acc[i][2] = fmaf(a.x, b0.z, fmaf(a.y, b1.z, fmaf(a.z, b2.z, fmaf(a.w, b3.z, acc[i][2]))));
                acc[i][3] = fmaf(a.x, b0.w, fmaf(a.y, b1.w, fmaf(a.z, b2.w, fmaf(a.w, b3.w, acc[i][3]))));
            }
        }
    }
}

// ---------- edge kernel: fused edge MLP chain + scatter aggregation ----------
__global__ __launch_bounds__(BLK) void egcl_edge(
    const float* __restrict__ h,
    const float* __restrict__ coord,
    const int* __restrict__ eidx,
    const float* __restrict__ We1, const float* __restrict__ be1,
    const float* __restrict__ We2, const float* __restrict__ be2,
    const float* __restrict__ Wc1, const float* __restrict__ bc1,
    const float* __restrict__ Wc2, const float* __restrict__ bc2,
    float* __restrict__ m_acc, float* __restrict__ c_acc)
{
    __shared__ float sA[TILE][264];   // edge_in (cols 0..256); later t1 (132..259), m (0..127)
    __shared__ float sW[32][128];
    __shared__ float sWlast[128];     // We1 row 256 (rad row)
    __shared__ float sWc2[128];
    __shared__ int   sR[TILE];
    __shared__ int   sC[TILE];
    __shared__ float sDif[TILE][3];

    const int tid  = threadIdx.x;
    const int trow = tid >> 5, tcol = tid & 31;
    const int e0   = blockIdx.x * TILE;

    if (tid < 128) { sWlast[tid] = We1[256 * 128 + tid]; sWc2[tid] = Wc2[tid]; }

    if (tid < TILE) {
        int e = e0 + tid;
        int r = eidx[e], c = eidx[NE + e];
        sR[tid] = r; sC[tid] = c;
        float dx = coord[r * 3 + 0] - coord[c * 3 + 0];
        float dy = coord[r * 3 + 1] - coord[c * 3 + 1];
        float dz = coord[r * 3 + 2] - coord[c * 3 + 2];
        float rad = fmaf(dx, dx, fmaf(dy, dy, dz * dz));
        float inv = 1.0f / (sqrtf(rad) + 1e-8f);
        sDif[tid][0] = dx * inv; sDif[tid][1] = dy * inv; sDif[tid][2] = dz * inv;
        sA[tid][256] = rad;
    }
    __syncthreads();

    {   // stage edge_in = [h[r] | h[c]] fp32, 8 threads per edge, float4
        int e = tid >> 3, l8 = tid & 7;
        const float4* pr = reinterpret_cast<const float4*>(h + (size_t)sR[e] * 128) + l8 * 4;
        const float4* pc = reinterpret_cast<const float4*>(h + (size_t)sC[e] * 128) + l8 * 4;
#pragma unroll
        for (int q = 0; q < 4; ++q) {
            *reinterpret_cast<float4*>(&sA[e][l8 * 16 + q * 4])       = pr[q];
            *reinterpret_cast<float4*>(&sA[e][128 + l8 * 16 + q * 4]) = pc[q];
        }
    }

    float acc[4][4];
    // ---- layer e1: [32,257] @ [257,128]  (rows 0..255 via GEMM, row 256 = rad)
#pragma unroll
    for (int i = 0; i < 4; ++i) { acc[i][0] = acc[i][1] = acc[i][2] = acc[i][3] = 0.f; }
    gemm_tile<256>(sA, sW, We1, 0, tid, trow, tcol, acc);
    float t1v[4][4];
#pragma unroll
    for (int i = 0; i < 4; ++i) {
        float rad = sA[trow * 4 + i][256];
#pragma unroll
        for (int jj = 0; jj < 4; ++jj) {
            int j = tcol * 4 + jj;
            t1v[i][jj] = silu(acc[i][jj] + rad * sWlast[j] + be1[j]);
        }
    }
    __syncthreads();   // all e1 reads of sA done
#pragma unroll
    for (int i = 0; i < 4; ++i)
        *reinterpret_cast<float4*>(&sA[trow * 4 + i][132 + tcol * 4]) =
            make_float4(t1v[i][0], t1v[i][1], t1v[i][2], t1v[i][3]);

    // ---- layer e2: m = silu(t1 @ We2 + be2)
#pragma unroll
    for (int i = 0; i < 4; ++i) { acc[i][0] = acc[i][1] = acc[i][2] = acc[i][3] = 0.f; }
    gemm_tile<128>(sA, sW, We2, 132, tid, trow, tcol, acc);
    __syncthreads();
#pragma unroll
    for (int i = 0; i < 4; ++i) {
        float4 mv;
        mv.x = silu(acc[i][0] + be2[tcol * 4 + 0]);
        mv.y = silu(acc[i][1] + be2[tcol * 4 + 1]);
        mv.z = silu(acc[i][2] + be2[tcol * 4 + 2]);
        mv.w = silu(acc[i][3] + be2[tcol * 4 + 3]);
        *reinterpret_cast<float4*>(&sA[trow * 4 + i][tcol * 4]) = mv;   // m -> cols 0..127
    }

    // ---- layer c1 + c2: w = silu(m @ Wc1 + bc1) . Wc2 + bc2
#pragma unroll
    for (int i = 0; i < 4; ++i) { acc[i][0] = acc[i][1] = acc[i][2] = acc[i][3] = 0.f; }
    gemm_tile<128>(sA, sW, Wc1, 0, tid, trow, tcol, acc);
    float p[4] = {0.f, 0.f, 0.f, 0.f};
#pragma unroll
    for (int i = 0; i < 4; ++i)
#pragma unroll
        for (int jj = 0; jj < 4; ++jj) {
            int j = tcol * 4 + jj;
            float t = silu(acc[i][jj] + bc1[j]);
            p[i] = fmaf(t, sWc2[j], p[i]);
        }
#pragma unroll
    for (int off = 16; off > 0; off >>= 1) {
#pragma unroll
        for (int i = 0; i < 4; ++i) p[i] += __shfl_down(p[i], off, 32);
    }
    if (tcol == 0) {
        float bc2v = bc2[0];
#pragma unroll
        for (int i = 0; i < 4; ++i) {
            int e = trow * 4 + i; int r = sR[e];
            float w = p[i] + bc2v;
            atomicAdd(&c_acc[(size_t)r * 3 + 0], sDif[e][0] * w);
            atomicAdd(&c_acc[(size_t)r * 3 + 1], sDif[e][1] * w);
            atomicAdd(&c_acc[(size_t)r * 3 + 2], sDif[e][2] * w);
        }
    }

    // ---- m_i scatter (lane-contiguous addresses -> L2-coalesced atomics)
#pragma unroll
    for (int t = 0; t < 16; ++t) {
        int idx = tid + t * BLK;
        int e = idx >> 7, j = idx & 127;
        atomicAdd(&m_acc[(size_t)sR[e] * 128 + j], sA[e][j]);
    }
}

// ---------- node kernel: vel MLP + coord_out + node MLP ----------
__global__ __launch_bounds__(BLK) void egcl_node(
    const float* __restrict__ h,
    const float* __restrict__ coord,
    const float* __restrict__ vel,
    const float* __restrict__ Wv1, const float* __restrict__ bv1,
    const float* __restrict__ Wv2, const float* __restrict__ bv2,
    const float* __restrict__ Wn1, const float* __restrict__ bn1,
    const float* __restrict__ Wn2, const float* __restrict__ bn2,
    const float* __restrict__ m_acc, const float* __restrict__ c_acc,
    float* __restrict__ out_h, float* __restrict__ out_c)
{
    __shared__ float sA[TILE][264];   // [h | m_i] (0..255), later t1 at 132..259
    __shared__ float sW[32][128];
    __shared__ float sWv2[128];

    const int tid  = threadIdx.x;
    const int trow = tid >> 5, tcol = tid & 31;
    const int n0   = blockIdx.x * TILE;

    if (tid < 128) sWv2[tid] = Wv2[tid];

    {   // stage [h[n] | m_i[n]]
        int e = tid >> 3, l8 = tid & 7;
        int n = n0 + e; int nn = (n < NN) ? n : (NN - 1);
        const float4* ph = reinterpret_cast<const float4*>(h + (size_t)nn * 128) + l8 * 4;
        const float4* pm = reinterpret_cast<const float4*>(m_acc + (size_t)nn * 128) + l8 * 4;
#pragma unroll
        for (int q = 0; q < 4; ++q) {
            *reinterpret_cast<float4*>(&sA[e][l8 * 16 + q * 4])       = ph[q];
            *reinterpret_cast<float4*>(&sA[e][128 + l8 * 16 + q * 4]) = pm[q];
        }
    }

    float acc[4][4];
    // ---- vel MLP: vw = silu(h @ Wv1 + bv1) . Wv2 + bv2
#pragma unroll
    for (int i = 0; i < 4; ++i) { acc[i][0] = acc[i][1] = acc[i][2] = acc[i][3] = 0.f; }
    gemm_tile<128>(sA, sW, Wv1, 0, tid, trow, tcol, acc);
    float p[4] = {0.f, 0.f, 0.f, 0.f};
#pragma unroll
    for (int i = 0; i < 4; ++i)
#pragma unroll
        for (int jj = 0; jj < 4; ++jj) {
            int j = tcol * 4 + jj;
            float t = silu(acc[i][jj] + bv1[j]);
            p[i] = fmaf(t, sWv2[j], p[i]);
        }
#pragma unroll
    for (int off = 16; off > 0; off >>= 1) {
#pragma unroll
        for (int i = 0; i < 4; ++i) p[i] += __shfl_down(p[i], off, 32);
    }
    if (tcol == 0) {
        float bv2v = bv2[0];
#pragma unroll
        for (int i = 0; i < 4; ++i) {
            int e = trow * 4 + i; int n = n0 + e;
            if (n < NN) {
                float vw = p[i] + bv2v;
#pragma unroll
                for (int d = 0; d < 3; ++d) {
                    float cv = coord[(size_t)n * 3 + d] + c_acc[(size_t)n * 3 + d]
                             + vel[(size_t)n * 3 + d] * vw;
                    out_c[(size_t)n * 3 + d] = cv;
                }
            }
        }
    }

    // ---- node MLP layer 1: t1 = silu([h|m_i] @ Wn1 + bn1)
#pragma unroll
    for (int i = 0; i < 4; ++i) { acc[i][0] = acc[i][1] = acc[i][2] = acc[i][3] = 0.f; }
    gemm_tile<256>(sA, sW, Wn1, 0, tid, trow, tcol, acc);
    float t1v[4][4];
#pragma unroll
    for (int i = 0; i < 4; ++i)
#pragma unroll
        for (int jj = 0; jj < 4; ++jj)
            t1v[i][jj] = silu(acc[i][jj] + bn1[tcol * 4 + jj]);
    __syncthreads();
#pragma unroll
    for (int i = 0; i < 4; ++i)
        *reinterpret_cast<float4*>(&sA[trow * 4 + i][132 + tcol * 4]) =
            make_float4(t1v[i][0], t1v[i][1], t1v[i][2], t1v[i][3]);

    // ---- node MLP layer 2 (no activation): h_out = t1 @ Wn2 + bn2
#pragma unroll
    for (int i = 0; i < 4; ++i) { acc[i][0] = acc[i][1] = acc[i][2] = acc[i][3] = 0.f; }
    gemm_tile<128>(sA, sW, Wn2, 132, tid, trow, tcol, acc);
#pragma unroll
    for (int i = 0; i < 4; ++i) {
        int e = trow * 4 + i; int n = n0 + e;
        if (n < NN) {
            float4 pk;
            pk.x = acc[i][0] + bn2[tcol * 4 + 0];
            pk.y = acc[i][1] + bn2[tcol * 4 + 1];
            pk.z = acc[i][2] + bn2[tcol * 4 + 2];
            pk.w = acc[i][3] + bn2[tcol * 4 + 3];
            *reinterpret_cast<float4*>(out_h + (size_t)n * 128 + tcol * 4) = pk;
        }
    }
}

extern "C" void kernel_launch(void* const* d_in, const int* in_sizes, int n_in,
                              void* d_out, int out_size, void* d_ws, size_t ws_size,
                              hipStream_t stream) {
    const float* h     = (const float*)d_in[0];
    const float* coord = (const float*)d_in[1];
    const float* vel   = (const float*)d_in[2];
    const int*   eidx  = (const int*)d_in[3];
    const float* We1 = (const float*)d_in[4];
    const float* be1 = (const float*)d_in[5];
    const float* We2 = (const float*)d_in[6];
    const float* be2 = (const float*)d_in[7];
    const float* Wc1 = (const float*)d_in[8];
    const float* bc1 = (const float*)d_in[9];
    const float* Wc2 = (const float*)d_in[10];
    const float* bc2 = (const float*)d_in[11];
    const float* Wv1 = (const float*)d_in[12];
    const float* bv1 = (const float*)d_in[13];
    const float* Wv2 = (const float*)d_in[14];
    const float* bv2 = (const float*)d_in[15];
    const float* Wn1 = (const float*)d_in[16];
    const float* bn1 = (const float*)d_in[17];
    const float* Wn2 = (const float*)d_in[18];
    const float* bn2 = (const float*)d_in[19];

    float* m_acc = (float*)d_ws;                                             // [NN,128] fp32
    float* c_acc = (float*)((char*)d_ws + (size_t)NN * 128 * sizeof(float)); // [NN,3] fp32
    size_t zb = (size_t)NN * 128 * sizeof(float) + (size_t)NN * 3 * sizeof(float);
    hipMemsetAsync(d_ws, 0, zb, stream);

    egcl_edge<<<NE / TILE, BLK, 0, stream>>>(h, coord, eidx,
                                             We1, be1, We2, be2, Wc1, bc1, Wc2, bc2,
                                             m_acc, c_acc);

    float* out_h = (float*)d_out;
    float* out_c = out_h + (size_t)NN * 128;
    egcl_node<<<(NN + TILE - 1) / TILE, BLK, 0, stream>>>(h, coord, vel,
                                                          Wv1, bv1, Wv2, bv2,
                                                          Wn1, bn1, Wn2, bn2,
                                                          m_acc, c_acc, out_h, out_c);
}

// Round 3
// 579.006 us; speedup vs baseline: 2.0928x; 2.0928x over previous
//
#include <hip/hip_runtime.h>
#include <stdint.h>

#define NN 50000
#define NE 500000
#define ET 64          // edges per block (edge kernel)
#define BLK 256
#define A2OFF 0        // shorts offset of t1 buffer inside uA
#define A3OFF 8704     // shorts offset of m buffer inside uA (64*136)

typedef __attribute__((ext_vector_type(8))) short bf16x8;
typedef __attribute__((ext_vector_type(4))) float f32x4;

__device__ __forceinline__ float silu(float x) { return x / (1.0f + __expf(-x)); }
__device__ __forceinline__ unsigned short f2bf(float f) {   // RNE float->bf16
    union { float f; unsigned int u; } v; v.f = f;
    return (unsigned short)((v.u + 0x7fffu + ((v.u >> 16) & 1u)) >> 16);
}
__device__ __forceinline__ unsigned int pack2(float a, float b) {
    return (unsigned int)f2bf(a) | ((unsigned int)f2bf(b) << 16);
}

// ---------------- prep kernels ----------------
__global__ void prep_h(const float* __restrict__ h, unsigned short* __restrict__ hb) {
    int i = blockIdx.x * 256 + threadIdx.x;          // over 1.6M float4 groups
    if (i < NN * 128 / 4) {
        float4 v = ((const float4*)h)[i];
        uint2 o; o.x = pack2(v.x, v.y); o.y = pack2(v.z, v.w);
        ((uint2*)hb)[i] = o;
    }
}

// Wt1[j][k]=We1[k][j] (k<256, natural); Wt2/Wt3: k sigma-permuted rows of We2/Wc1.
// sigma(col) = (col%16)*8 + col/16  => orig_k(ks) = (ks%8)*16 + ks/8
__global__ void prep_w(const float* __restrict__ We1, const float* __restrict__ We2,
                       const float* __restrict__ Wc1,
                       unsigned short* __restrict__ Wt1, unsigned short* __restrict__ Wt2,
                       unsigned short* __restrict__ Wt3) {
    int i = blockIdx.x * 256 + threadIdx.x;
    if (i < 32768) {
        int j = i >> 8, k = i & 255;
        Wt1[i] = f2bf(We1[k * 128 + j]);
    } else if (i < 49152) {
        int t = i - 32768; int j = t >> 7, ks = t & 127;
        int k0 = (ks & 7) * 16 + (ks >> 3);
        Wt2[t] = f2bf(We2[k0 * 128 + j]);
    } else if (i < 65536) {
        int t = i - 49152; int j = t >> 7, ks = t & 127;
        int k0 = (ks & 7) * 16 + (ks >> 3);
        Wt3[t] = f2bf(Wc1[k0 * 128 + j]);
    }
}

// ---------------- MFMA layer core ----------------
// acc[ct] += A[rows=wave strip][K] @ Wt^T, A bf16 row-major (astride elems),
// Wt[j][k] bf16 (wstride elems), staged per 32-k chunk into sB[128][40].
__device__ __forceinline__ void mfma_layer(
    const unsigned short* __restrict__ Wt, int wstride, int kchunks,
    const unsigned short* aBase, int astride,
    unsigned short* sB, int wv, int l16, int q, f32x4* acc)
{
    const int tid = threadIdx.x;
    const int j = tid >> 1, half = tid & 1;
    for (int kc = 0; kc < kchunks * 32; kc += 32) {
        __syncthreads();
        const uint4* s = (const uint4*)(Wt + (size_t)j * wstride + kc + half * 16);
        uint4 v0 = s[0], v1 = s[1];
        uint4* d = (uint4*)(sB + j * 40 + half * 16);
        d[0] = v0; d[1] = v1;
        __syncthreads();
        bf16x8 a = *(const bf16x8*)(aBase + (size_t)(wv * 16 + l16) * astride + kc + q * 8);
#pragma unroll
        for (int ct = 0; ct < 8; ++ct) {
            bf16x8 b = *(const bf16x8*)(sB + (ct * 16 + l16) * 40 + q * 8);
            acc[ct] = __builtin_amdgcn_mfma_f32_16x16x32_bf16(a, b, acc[ct], 0, 0, 0);
        }
    }
}

// ---------------- edge kernel: MFMA edge-MLP chain + scatter ----------------
__global__ __launch_bounds__(BLK, 3) void egcl_edge(
    const float* __restrict__ coord,
    const int* __restrict__ eidx,
    const unsigned short* __restrict__ hb,
    const unsigned short* __restrict__ Wt1,
    const unsigned short* __restrict__ Wt2,
    const unsigned short* __restrict__ Wt3,
    const float* __restrict__ We1,               // for row 256 (rad row, fp32)
    const float* __restrict__ be1, const float* __restrict__ be2,
    const float* __restrict__ bc1,
    const float* __restrict__ Wc2, const float* __restrict__ bc2,
    float* __restrict__ m_acc, float* __restrict__ c_acc)
{
    __shared__ unsigned short uA[17408];         // A1[64][264] bf16, aliased by A2/A3 [64][136]
    __shared__ unsigned short sB[128 * 40];
    __shared__ float sRad[ET], sDif[ET][3];
    __shared__ float sWlast[128], sWc2f[128], sBe1[128], sBe2[128], sBc1[128];
    __shared__ int   sR[ET];

    const int tid = threadIdx.x;
    const int wv = tid >> 6, lane = tid & 63, q = lane >> 4, l16 = lane & 15;
    const int e0 = blockIdx.x * ET;
    const int nval = (NE - e0 < ET) ? (NE - e0) : ET;

    if (tid < 128) {
        sWlast[tid] = We1[256 * 128 + tid]; sWc2f[tid] = Wc2[tid];
        sBe1[tid] = be1[tid]; sBe2[tid] = be2[tid]; sBc1[tid] = bc1[tid];
    }
    if (tid < ET) {
        int e = e0 + tid; if (e >= NE) e = NE - 1;
        int r = eidx[e], c = eidx[NE + e];
        sR[tid] = r;
        float dx = coord[r * 3 + 0] - coord[c * 3 + 0];
        float dy = coord[r * 3 + 1] - coord[c * 3 + 1];
        float dz = coord[r * 3 + 2] - coord[c * 3 + 2];
        float rad = fmaf(dx, dx, fmaf(dy, dy, dz * dz));
        float inv = 1.0f / (sqrtf(rad) + 1e-8f);
        sRad[tid] = rad;
        sDif[tid][0] = dx * inv; sDif[tid][1] = dy * inv; sDif[tid][2] = dz * inv;
    }
    {   // stage A1 = [h[r] | h[c]] bf16, 4 threads/edge, 128B each
        int le = tid >> 2, p = tid & 3;
        int e = e0 + le; if (e >= NE) e = NE - 1;
        int node = (p < 2) ? eidx[e] : eidx[NE + e];
        const uint4* src = (const uint4*)(hb + (size_t)node * 128) + (p & 1) * 8;
        unsigned short* dst = uA + le * 264 + (p >> 1) * 128 + (p & 1) * 64;
#pragma unroll
        for (int t = 0; t < 8; ++t) ((uint4*)dst)[t] = src[t];
    }
    // (mfma_layer's first __syncthreads orders staging before fragment reads)

    f32x4 acc[8];
#pragma unroll
    for (int ct = 0; ct < 8; ++ct) acc[ct] = (f32x4){0.f, 0.f, 0.f, 0.f};

    // ---- e1: edge_in[64,256] @ We1 (+ rad rank-1 term fp32)
    mfma_layer(Wt1, 256, 8, uA, 264, sB, wv, l16, q, acc);
    float radv[4];
#pragma unroll
    for (int r = 0; r < 4; ++r) radv[r] = sRad[wv * 16 + q * 4 + r];
    __syncthreads();     // all A1 fragment reads complete before A2 overwrite
#pragma unroll
    for (int r = 0; r < 4; ++r) {
        float v[8];
#pragma unroll
        for (int ct = 0; ct < 8; ++ct) {
            int col = ct * 16 + l16;
            v[ct] = silu(acc[ct][r] + radv[r] * sWlast[col] + sBe1[col]);
        }
        uint4 pk; pk.x = pack2(v[0], v[1]); pk.y = pack2(v[2], v[3]);
        pk.z = pack2(v[4], v[5]); pk.w = pack2(v[6], v[7]);
        *(uint4*)(uA + A2OFF + (wv * 16 + q * 4 + r) * 136 + l16 * 8) = pk;  // sigma order
    }

    // ---- e2: m = silu(t1 @ We2 + be2)
#pragma unroll
    for (int ct = 0; ct < 8; ++ct) acc[ct] = (f32x4){0.f, 0.f, 0.f, 0.f};
    mfma_layer(Wt2, 128, 4, uA + A2OFF, 136, sB, wv, l16, q, acc);
#pragma unroll
    for (int r = 0; r < 4; ++r) {
        int row = wv * 16 + q * 4 + r;
        float v[8];
#pragma unroll
        for (int ct = 0; ct < 8; ++ct) v[ct] = silu(acc[ct][r] + sBe2[ct * 16 + l16]);
        uint4 pk; pk.x = pack2(v[0], v[1]); pk.y = pack2(v[2], v[3]);
        pk.z = pack2(v[4], v[5]); pk.w = pack2(v[6], v[7]);
        *(uint4*)(uA + A3OFF + row * 136 + l16 * 8) = pk;   // A3 region idle since e1 + barriers
        if (row < nval) {                                    // m_i scatter, fp32 from regs
            float* mrow = m_acc + (size_t)sR[row] * 128;
#pragma unroll
            for (int ct = 0; ct < 8; ++ct) atomicAdd(mrow + ct * 16 + l16, v[ct]);
        }
    }

    // ---- c1+c2: w = silu(m @ Wc1 + bc1) . Wc2 + bc2
#pragma unroll
    for (int ct = 0; ct < 8; ++ct) acc[ct] = (f32x4){0.f, 0.f, 0.f, 0.f};
    mfma_layer(Wt3, 128, 4, uA + A3OFF, 136, sB, wv, l16, q, acc);
    float bc2v = bc2[0];
    float p[4];
#pragma unroll
    for (int r = 0; r < 4; ++r) {
        float s = 0.f;
#pragma unroll
        for (int ct = 0; ct < 8; ++ct) {
            int col = ct * 16 + l16;
            float t = silu(acc[ct][r] + sBc1[col]);
            s = fmaf(t, sWc2f[col], s);
        }
        p[r] = s;
    }
#pragma unroll
    for (int m = 1; m < 16; m <<= 1) {
#pragma unroll
        for (int r = 0; r < 4; ++r) p[r] += __shfl_xor(p[r], m, 16);
    }
    if (l16 == 0) {
#pragma unroll
        for (int r = 0; r < 4; ++r) {
            int row = wv * 16 + q * 4 + r;
            if (row < nval) {
                int rn = sR[row]; float w = p[r] + bc2v;
                atomicAdd(&c_acc[(size_t)rn * 3 + 0], sDif[row][0] * w);
                atomicAdd(&c_acc[(size_t)rn * 3 + 1], sDif[row][1] * w);
                atomicAdd(&c_acc[(size_t)rn * 3 + 2], sDif[row][2] * w);
            }
        }
    }
}

// ---------------- node kernel (unchanged fp32 path from R2) ----------------
template <int K>
__device__ __forceinline__ void gemm_tile(
    float (&sA)[32][264], float (&sW)[32][128],
    const float* __restrict__ W, int acol,
    int tid, int trow, int tcol, float (&acc)[4][4])
{
    const float4* W4 = reinterpret_cast<const float4*>(W);
    for (int k0 = 0; k0 < K; k0 += 32) {
        __syncthreads();
#pragma unroll
        for (int t = 0; t < 4; ++t) {
            int idx = tid + t * BLK;
            int kk = idx >> 5, c4 = idx & 31;
            *reinterpret_cast<float4*>(&sW[kk][c4 * 4]) = W4[(size_t)(k0 + kk) * 32 + c4];
        }
        __syncthreads();
#pragma unroll
        for (int kq = 0; kq < 8; ++kq) {
            const float4 b0 = *reinterpret_cast<const float4*>(&sW[4 * kq + 0][tcol * 4]);
            const float4 b1 = *reinterpret_cast<const float4*>(&sW[4 * kq + 1][tcol * 4]);
            const float4 b2 = *reinterpret_cast<const float4*>(&sW[4 * kq + 2][tcol * 4]);
            const float4 b3 = *reinterpret_cast<const float4*>(&sW[4 * kq + 3][tcol * 4]);
#pragma unroll
            for (int i = 0; i < 4; ++i) {
                const float4 a = *reinterpret_cast<const float4*>(&sA[trow * 4 + i][acol + k0 + 4 * kq]);
                acc[i][0] = fmaf(a.x, b0.x, fmaf(a.y, b1.x, fmaf(a.z, b2.x, fmaf(a.w, b3.x, acc[i][0]))));
                acc[i][1] = fmaf(a.x, b0.y, fmaf(a.y, b1.y, fmaf(a.z, b2.y, fmaf(a.w, b3.y, acc[i][1]))));
                acc[i][2] = fmaf(a.x, b0.z, fmaf(a.y, b1.z, fmaf(a.z, b2.z, fmaf(a.w, b3.z, acc[i][2]))));
                acc[i][3] = fmaf(a.x, b0.w, fmaf(a.y, b1.w, fmaf(a.z, b2.w, fmaf(a.w, b3.w, acc[i][3]))));
            }
        }
    }
}

__global__ __launch_bounds__(BLK) void egcl_node(
    const float* __restrict__ h,
    const float* __restrict__ coord,
    const float* __restrict__ vel,
    const float* __restrict__ Wv1, const float* __restrict__ bv1,
    const float* __restrict__ Wv2, const float* __restrict__ bv2,
    const float* __restrict__ Wn1, const float* __restrict__ bn1,
    const float* __restrict__ Wn2, const float* __restrict__ bn2,
    const float* __restrict__ m_acc, const float* __restrict__ c_acc,
    float* __restrict__ out_h, float* __restrict__ out_c)
{
    __shared__ float sA[32][264];
    __shared__ float sW[32][128];
    __shared__ float sWv2[128];

    const int tid  = threadIdx.x;
    const int trow = tid >> 5, tcol = tid & 31;
    const int n0   = blockIdx.x * 32;

    if (tid < 128) sWv2[tid] = Wv2[tid];

    {
        int e = tid >> 3, l8 = tid & 7;
        int n = n0 + e; int nn = (n < NN) ? n : (NN - 1);
        const float4* ph = reinterpret_cast<const float4*>(h + (size_t)nn * 128) + l8 * 4;
        const float4* pm = reinterpret_cast<const float4*>(m_acc + (size_t)nn * 128) + l8 * 4;
#pragma unroll
        for (int qq = 0; qq < 4; ++qq) {
            *reinterpret_cast<float4*>(&sA[e][l8 * 16 + qq * 4])       = ph[qq];
            *reinterpret_cast<float4*>(&sA[e][128 + l8 * 16 + qq * 4]) = pm[qq];
        }
    }

    float acc[4][4];
#pragma unroll
    for (int i = 0; i < 4; ++i) { acc[i][0] = acc[i][1] = acc[i][2] = acc[i][3] = 0.f; }
    gemm_tile<128>(sA, sW, Wv1, 0, tid, trow, tcol, acc);
    float p[4] = {0.f, 0.f, 0.f, 0.f};
#pragma unroll
    for (int i = 0; i < 4; ++i)
#pragma unroll
        for (int jj = 0; jj < 4; ++jj) {
            int j = tcol * 4 + jj;
            float t = silu(acc[i][jj] + bv1[j]);
            p[i] = fmaf(t, sWv2[j], p[i]);
        }
#pragma unroll
    for (int off = 16; off > 0; off >>= 1) {
#pragma unroll
        for (int i = 0; i < 4; ++i) p[i] += __shfl_down(p[i], off, 32);
    }
    if (tcol == 0) {
        float bv2v = bv2[0];
#pragma unroll
        for (int i = 0; i < 4; ++i) {
            int e = trow * 4 + i; int n = n0 + e;
            if (n < NN) {
                float vw = p[i] + bv2v;
#pragma unroll
                for (int d = 0; d < 3; ++d) {
                    float cv = coord[(size_t)n * 3 + d] + c_acc[(size_t)n * 3 + d]
                             + vel[(size_t)n * 3 + d] * vw;
                    out_c[(size_t)n * 3 + d] = cv;
                }
            }
        }
    }

#pragma unroll
    for (int i = 0; i < 4; ++i) { acc[i][0] = acc[i][1] = acc[i][2] = acc[i][3] = 0.f; }
    gemm_tile<256>(sA, sW, Wn1, 0, tid, trow, tcol, acc);
    float t1v[4][4];
#pragma unroll
    for (int i = 0; i < 4; ++i)
#pragma unroll
        for (int jj = 0; jj < 4; ++jj)
            t1v[i][jj] = silu(acc[i][jj] + bn1[tcol * 4 + jj]);
    __syncthreads();
#pragma unroll
    for (int i = 0; i < 4; ++i)
        *reinterpret_cast<float4*>(&sA[trow * 4 + i][132 + tcol * 4]) =
            make_float4(t1v[i][0], t1v[i][1], t1v[i][2], t1v[i][3]);

#pragma unroll
    for (int i = 0; i < 4; ++i) { acc[i][0] = acc[i][1] = acc[i][2] = acc[i][3] = 0.f; }
    gemm_tile<128>(sA, sW, Wn2, 132, tid, trow, tcol, acc);
#pragma unroll
    for (int i = 0; i < 4; ++i) {
        int e = trow * 4 + i; int n = n0 + e;
        if (n < NN) {
            float4 pk;
            pk.x = acc[i][0] + bn2[tcol * 4 + 0];
            pk.y = acc[i][1] + bn2[tcol * 4 + 1];
            pk.z = acc[i][2] + bn2[tcol * 4 + 2];
            pk.w = acc[i][3] + bn2[tcol * 4 + 3];
            *reinterpret_cast<float4*>(out_h + (size_t)n * 128 + tcol * 4) = pk;
        }
    }
}

extern "C" void kernel_launch(void* const* d_in, const int* in_sizes, int n_in,
                              void* d_out, int out_size, void* d_ws, size_t ws_size,
                              hipStream_t stream) {
    const float* h     = (const float*)d_in[0];
    const float* coord = (const float*)d_in[1];
    const float* vel   = (const float*)d_in[2];
    const int*   eidx  = (const int*)d_in[3];
    const float* We1 = (const float*)d_in[4];
    const float* be1 = (const float*)d_in[5];
    const float* We2 = (const float*)d_in[6];
    const float* be2 = (const float*)d_in[7];
    const float* Wc1 = (const float*)d_in[8];
    const float* bc1 = (const float*)d_in[9];
    const float* Wc2 = (const float*)d_in[10];
    const float* bc2 = (const float*)d_in[11];
    const float* Wv1 = (const float*)d_in[12];
    const float* bv1 = (const float*)d_in[13];
    const float* Wv2 = (const float*)d_in[14];
    const float* bv2 = (const float*)d_in[15];
    const float* Wn1 = (const float*)d_in[16];
    const float* bn1 = (const float*)d_in[17];
    const float* Wn2 = (const float*)d_in[18];
    const float* bn2 = (const float*)d_in[19];

    char* ws = (char*)d_ws;
    float* m_acc = (float*)ws;                                 // [NN,128] f32 = 25.6 MB
    float* c_acc = (float*)(ws + 25600000);                    // [NN,3]  f32
    unsigned short* hb  = (unsigned short*)(ws + 26200064);    // [NN,128] bf16
    unsigned short* Wt1 = (unsigned short*)(ws + 39000064);    // [128][256] bf16
    unsigned short* Wt2 = (unsigned short*)(ws + 39065600);    // [128][128] bf16 (sigma-k)
    unsigned short* Wt3 = (unsigned short*)(ws + 39098368);    // [128][128] bf16 (sigma-k)

    hipMemsetAsync(d_ws, 0, 26200000, stream);
    prep_h<<<6250, 256, 0, stream>>>(h, hb);
    prep_w<<<256, 256, 0, stream>>>(We1, We2, Wc1, Wt1, Wt2, Wt3);

    egcl_edge<<<(NE + ET - 1) / ET, BLK, 0, stream>>>(
        coord, eidx, hb, Wt1, Wt2, Wt3,
        We1, be1, be2, bc1, Wc2, bc2, m_acc, c_acc);

    float* out_h = (float*)d_out;
    float* out_c = out_h + (size_t)NN * 128;
    egcl_node<<<(NN + 31) / 32, BLK, 0, stream>>>(h, coord, vel,
                                                  Wv1, bv1, Wv2, bv2,
                                                  Wn1, bn1, Wn2, bn2,
                                                  m_acc, c_acc, out_h, out_c);
}